// Round 1
// baseline (510.149 us; speedup 1.0000x reference)
//
#include <hip/hip_runtime.h>
#include <hip/hip_bf16.h>

// ---------------------------------------------------------------------------
// GCN 2-layer inference:
//   h1 = relu( D^-1/2 (A+I) D^-1/2 (x @ W1) + b1 )
//   out = softmax( D^-1/2 (A+I) D^-1/2 (h1 @ W2) + b2 )
// deg = in-degree by dst + 1. Both layers share edge_index/deg.
//
// Pipeline (all on `stream`):
//   memset(cnt,cursor) -> count -> scan(+dinv) -> fill(CSR by dst)
//   -> gemm1 (epilogue: *dinv[row]) -> agg1 (+b1, relu)
//   -> gemm2 (epilogue: *dinv[row]) -> agg2 (+b2, softmax)
// ---------------------------------------------------------------------------

#define F_IN 512
#define NHID 128
#define NCLS 64

// ---------------- CSR build ----------------

__global__ void count_kernel(const int* __restrict__ dst, int* __restrict__ cnt, int E) {
    int e = blockIdx.x * blockDim.x + threadIdx.x;
    if (e < E) atomicAdd(&cnt[dst[e]], 1);
}

__global__ __launch_bounds__(1024) void scan_kernel(const int* __restrict__ cnt,
        int* __restrict__ row_ptr, float* __restrict__ dinv, int N) {
    __shared__ int wsum[16];
    __shared__ int carry;
    const int tid = threadIdx.x;
    const int lane = tid & 63, wid = tid >> 6;
    if (tid == 0) carry = 0;
    __syncthreads();
    for (int base = 0; base < N; base += 1024) {
        int i = base + tid;
        int v = (i < N) ? cnt[i] : 0;
        if (i < N) dinv[i] = rsqrtf((float)v + 1.0f);
        // wave-inclusive scan
        int s = v;
        #pragma unroll
        for (int d = 1; d < 64; d <<= 1) {
            int t = __shfl_up(s, d);
            if (lane >= d) s += t;
        }
        if (lane == 63) wsum[wid] = s;
        __syncthreads();
        int woff = 0;
        for (int w = 0; w < wid; ++w) woff += wsum[w];
        int excl = woff + s - v;
        if (i < N) row_ptr[i] = carry + excl;
        int blocktotal = 0;
        #pragma unroll
        for (int w = 0; w < 16; ++w) blocktotal += wsum[w];
        __syncthreads();
        if (tid == 0) carry += blocktotal;
        __syncthreads();
    }
    if (tid == 0) row_ptr[N] = carry;
}

__global__ void fill_kernel(const int* __restrict__ src, const int* __restrict__ dst,
        const int* __restrict__ row_ptr, int* __restrict__ cursor,
        int* __restrict__ col, int E) {
    int e = blockIdx.x * blockDim.x + threadIdx.x;
    if (e < E) {
        int d = dst[e];
        int pos = row_ptr[d] + atomicAdd(&cursor[d], 1);
        col[pos] = src[e];
    }
}

// ---------------- GEMM1: Hs = (x @ W1) * dinv[row]  [N,128] ----------------
// BM=64, BN=128, BK=32, 256 threads, thread tile 4x8.

__global__ __launch_bounds__(256) void gemm1_kernel(const float* __restrict__ X,
        const float* __restrict__ W1, const float* __restrict__ dinv,
        float* __restrict__ Hs, int M) {
    __shared__ float As[32][65];   // [k][m], +1 pad
    __shared__ float Bs[32][128];  // [k][n]
    const int tid = threadIdx.x;
    const int m0 = blockIdx.x * 64;
    const int tx = tid & 15;   // 16 col groups of 8
    const int ty = tid >> 4;   // 16 row groups of 4
    float acc[4][8] = {};

    for (int k0 = 0; k0 < F_IN; k0 += 32) {
        // A tile: 64 rows x 32 k  -> 512 float4, 2 per thread (store transposed)
        #pragma unroll
        for (int i = 0; i < 2; ++i) {
            int v = tid + i * 256;
            int r = v >> 3;
            int c4 = (v & 7) * 4;
            int gr = m0 + r; if (gr > M - 1) gr = M - 1;
            const float4 a = *reinterpret_cast<const float4*>(&X[(size_t)gr * F_IN + k0 + c4]);
            As[c4 + 0][r] = a.x; As[c4 + 1][r] = a.y;
            As[c4 + 2][r] = a.z; As[c4 + 3][r] = a.w;
        }
        // B tile: 32 k x 128 n -> 1024 float4, 4 per thread
        #pragma unroll
        for (int i = 0; i < 4; ++i) {
            int v = tid + i * 256;
            int r = v >> 5;
            int c4 = (v & 31) * 4;
            *reinterpret_cast<float4*>(&Bs[r][c4]) =
                *reinterpret_cast<const float4*>(&W1[(size_t)(k0 + r) * NHID + c4]);
        }
        __syncthreads();
        #pragma unroll
        for (int k = 0; k < 32; ++k) {
            float a[4], b[8];
            #pragma unroll
            for (int r = 0; r < 4; ++r) a[r] = As[k][ty * 4 + r];
            #pragma unroll
            for (int c = 0; c < 8; ++c) b[c] = Bs[k][tx * 8 + c];
            #pragma unroll
            for (int r = 0; r < 4; ++r)
                #pragma unroll
                for (int c = 0; c < 8; ++c)
                    acc[r][c] = fmaf(a[r], b[c], acc[r][c]);
        }
        __syncthreads();
    }
    #pragma unroll
    for (int r = 0; r < 4; ++r) {
        int gr = m0 + ty * 4 + r;
        if (gr < M) {
            float di = dinv[gr];
            #pragma unroll
            for (int c = 0; c < 8; c += 4) {
                float4 o;
                o.x = acc[r][c + 0] * di; o.y = acc[r][c + 1] * di;
                o.z = acc[r][c + 2] * di; o.w = acc[r][c + 3] * di;
                *reinterpret_cast<float4*>(&Hs[(size_t)gr * NHID + tx * 8 + c]) = o;
            }
        }
    }
}

// ---------------- AGG1: Y = relu(dinv[i]*(Hs[i] + sum Hs[src]) + b1) ----------------

__global__ __launch_bounds__(128) void agg1_kernel(const float* __restrict__ Hs,
        const int* __restrict__ row_ptr, const int* __restrict__ col,
        const float* __restrict__ dinv, const float* __restrict__ b1,
        float* __restrict__ Y) {
    const int i = blockIdx.x;
    const int c = threadIdx.x;
    const int beg = row_ptr[i], end = row_ptr[i + 1];
    float acc = Hs[(size_t)i * NHID + c];   // self (already scaled by dinv[i])
    int e = beg;
    for (; e + 4 <= end; e += 4) {
        int s0 = col[e], s1 = col[e + 1], s2 = col[e + 2], s3 = col[e + 3];
        float v0 = Hs[(size_t)s0 * NHID + c];
        float v1 = Hs[(size_t)s1 * NHID + c];
        float v2 = Hs[(size_t)s2 * NHID + c];
        float v3 = Hs[(size_t)s3 * NHID + c];
        acc += (v0 + v1) + (v2 + v3);
    }
    for (; e < end; ++e) acc += Hs[(size_t)col[e] * NHID + c];
    float v = fmaf(acc, dinv[i], b1[c]);
    Y[(size_t)i * NHID + c] = fmaxf(v, 0.0f);
}

// ---------------- GEMM2: H2s = (Y @ W2) * dinv[row]  [N,64] ----------------
// 16 rows/block, 256 threads (4 row-groups x 64 cols), 4 rows per thread.

__global__ __launch_bounds__(256) void gemm2_kernel(const float* __restrict__ Y,
        const float* __restrict__ W2, const float* __restrict__ dinv,
        float* __restrict__ H2s, int N) {
    __shared__ float Ws[NHID][NCLS];  // 32 KB
    __shared__ float Ys[16][NHID];    // 8 KB
    const int tid = threadIdx.x;
    const int i0 = blockIdx.x * 16;
    // W2: 8192 floats = 2048 float4, 8 per thread
    #pragma unroll
    for (int t = 0; t < 8; ++t) {
        int v = tid + t * 256;
        int k = v >> 4;
        int c4 = (v & 15) * 4;
        *reinterpret_cast<float4*>(&Ws[k][c4]) =
            *reinterpret_cast<const float4*>(&W2[(size_t)k * NCLS + c4]);
    }
    // Y rows: 16 x 128 = 512 float4, 2 per thread
    #pragma unroll
    for (int t = 0; t < 2; ++t) {
        int v = tid + t * 256;
        int r = v >> 5;
        int c4 = (v & 31) * 4;
        int gr = i0 + r; if (gr > N - 1) gr = N - 1;
        *reinterpret_cast<float4*>(&Ys[r][c4]) =
            *reinterpret_cast<const float4*>(&Y[(size_t)gr * NHID + c4]);
    }
    __syncthreads();
    const int c = tid & 63;
    const int rg = tid >> 6;
    float acc[4] = {0.f, 0.f, 0.f, 0.f};
    #pragma unroll 8
    for (int k = 0; k < NHID; ++k) {
        float w = Ws[k][c];
        #pragma unroll
        for (int j = 0; j < 4; ++j)
            acc[j] = fmaf(Ys[rg * 4 + j][k], w, acc[j]);
    }
    #pragma unroll
    for (int j = 0; j < 4; ++j) {
        int gr = i0 + rg * 4 + j;
        if (gr < N) H2s[(size_t)gr * NCLS + c] = acc[j] * dinv[gr];
    }
}

// ---------------- AGG2 + softmax ----------------

__global__ __launch_bounds__(64) void agg2_kernel(const float* __restrict__ H2s,
        const int* __restrict__ row_ptr, const int* __restrict__ col,
        const float* __restrict__ dinv, const float* __restrict__ b2,
        float* __restrict__ out) {
    const int i = blockIdx.x;
    const int c = threadIdx.x;
    const int beg = row_ptr[i], end = row_ptr[i + 1];
    float acc = H2s[(size_t)i * NCLS + c];
    int e = beg;
    for (; e + 4 <= end; e += 4) {
        int s0 = col[e], s1 = col[e + 1], s2 = col[e + 2], s3 = col[e + 3];
        float v0 = H2s[(size_t)s0 * NCLS + c];
        float v1 = H2s[(size_t)s1 * NCLS + c];
        float v2 = H2s[(size_t)s2 * NCLS + c];
        float v3 = H2s[(size_t)s3 * NCLS + c];
        acc += (v0 + v1) + (v2 + v3);
    }
    for (; e < end; ++e) acc += H2s[(size_t)col[e] * NCLS + c];
    float v = fmaf(acc, dinv[i], b2[c]);
    // softmax across 64 lanes
    float m = v;
    #pragma unroll
    for (int d = 32; d >= 1; d >>= 1) m = fmaxf(m, __shfl_xor(m, d));
    float ex = __expf(v - m);
    float sum = ex;
    #pragma unroll
    for (int d = 32; d >= 1; d >>= 1) sum += __shfl_xor(sum, d);
    out[(size_t)i * NCLS + c] = ex / sum;
}

// ---------------- launch ----------------

extern "C" void kernel_launch(void* const* d_in, const int* in_sizes, int n_in,
                              void* d_out, int out_size, void* d_ws, size_t ws_size,
                              hipStream_t stream) {
    const float* x  = (const float*)d_in[0];
    const int*   ei = (const int*)d_in[1];
    const float* W1 = (const float*)d_in[2];
    const float* b1 = (const float*)d_in[3];
    const float* W2 = (const float*)d_in[4];
    const float* b2 = (const float*)d_in[5];
    const int N = in_sizes[0] / F_IN;
    const int E = in_sizes[1] / 2;
    const int* src = ei;
    const int* dst = ei + E;
    float* out = (float*)d_out;

    const int Npad = (N + 63) & ~63;
    const int Epad = (E + 63) & ~63;
    int*   cnt     = (int*)d_ws;               // Npad
    int*   cursor  = cnt + Npad;               // Npad
    int*   row_ptr = cursor + Npad;            // Npad (>= N+1)
    float* dinv    = (float*)(row_ptr + Npad); // Npad
    int*   col     = (int*)(dinv + Npad);      // Epad
    float* Hs      = (float*)(col + Epad);     // Npad*128
    float* Y       = Hs + (size_t)Npad * NHID; // Npad*128
    float* H2s     = Hs;                       // reuse (Hs dead after agg1)

    hipMemsetAsync(cnt, 0, (size_t)2 * Npad * sizeof(int), stream);
    count_kernel<<<(E + 255) / 256, 256, 0, stream>>>(dst, cnt, E);
    scan_kernel<<<1, 1024, 0, stream>>>(cnt, row_ptr, dinv, N);
    fill_kernel<<<(E + 255) / 256, 256, 0, stream>>>(src, dst, row_ptr, cursor, col, E);
    gemm1_kernel<<<(N + 63) / 64, 256, 0, stream>>>(x, W1, dinv, Hs, N);
    agg1_kernel<<<N, 128, 0, stream>>>(Hs, row_ptr, col, dinv, b1, Y);
    gemm2_kernel<<<(N + 15) / 16, 256, 0, stream>>>(Y, W2, dinv, H2s, N);
    agg2_kernel<<<N, 64, 0, stream>>>(H2s, row_ptr, col, dinv, b2, out);
}

// Round 2
// 452.065 us; speedup vs baseline: 1.1285x; 1.1285x over previous
//
#include <hip/hip_runtime.h>
#include <hip/hip_bf16.h>

// ---------------------------------------------------------------------------
// GCN 2-layer inference:
//   h1 = relu( D^-1/2 (A+I) D^-1/2 (x @ W1) + b1 )
//   out = softmax( D^-1/2 (A+I) D^-1/2 (h1 @ W2) + b2 )
//
// Pipeline: memset -> count -> scan(+dinv) -> fill(CSR) -> prepW (split W1
// into bf16 hi/lo, transposed) -> gemm1_mfma (split-bf16 3-product MFMA,
// epilogue *dinv[row]) -> agg1 (+b1, relu) -> gemm2 -> agg2 (+b2, softmax)
// ---------------------------------------------------------------------------

#define F_IN 512
#define NHID 128
#define NCLS 64

typedef __attribute__((ext_vector_type(8))) short short8;
typedef __attribute__((ext_vector_type(4))) float f32x4;

__device__ __forceinline__ unsigned f2u(float f) { union { float f; unsigned u; } v; v.f = f; return v.u; }
__device__ __forceinline__ float u2f(unsigned u) { union { unsigned u; float f; } v; v.u = u; return v.f; }

// ---------------- CSR build ----------------

__global__ void count_kernel(const int* __restrict__ dst, int* __restrict__ cnt, int E) {
    int e = blockIdx.x * blockDim.x + threadIdx.x;
    if (e < E) atomicAdd(&cnt[dst[e]], 1);
}

__global__ __launch_bounds__(1024) void scan_kernel(const int* __restrict__ cnt,
        int* __restrict__ row_ptr, float* __restrict__ dinv, int N) {
    __shared__ int wsum[16];
    __shared__ int carry;
    const int tid = threadIdx.x;
    const int lane = tid & 63, wid = tid >> 6;
    if (tid == 0) carry = 0;
    __syncthreads();
    for (int base = 0; base < N; base += 1024) {
        int i = base + tid;
        int v = (i < N) ? cnt[i] : 0;
        if (i < N) dinv[i] = rsqrtf((float)v + 1.0f);
        int s = v;
        #pragma unroll
        for (int d = 1; d < 64; d <<= 1) {
            int t = __shfl_up(s, d);
            if (lane >= d) s += t;
        }
        if (lane == 63) wsum[wid] = s;
        __syncthreads();
        int woff = 0;
        for (int w = 0; w < wid; ++w) woff += wsum[w];
        int excl = woff + s - v;
        if (i < N) row_ptr[i] = carry + excl;
        int blocktotal = 0;
        #pragma unroll
        for (int w = 0; w < 16; ++w) blocktotal += wsum[w];
        __syncthreads();
        if (tid == 0) carry += blocktotal;
        __syncthreads();
    }
    if (tid == 0) row_ptr[N] = carry;
}

__global__ void fill_kernel(const int* __restrict__ src, const int* __restrict__ dst,
        const int* __restrict__ row_ptr, int* __restrict__ cursor,
        int* __restrict__ col, int E) {
    int e = blockIdx.x * blockDim.x + threadIdx.x;
    if (e < E) {
        int d = dst[e];
        int pos = row_ptr[d] + atomicAdd(&cursor[d], 1);
        col[pos] = src[e];
    }
}

// ---------------- prepW: W1 [512][128] f32 -> WhiT/WloT [128][512] bf16 ----------------
// Truncation split: hi = upper 16 bits, lo = bf16_trunc(w - hi). hi+lo
// reproduces w to 2^-16 rel; dropped lo*lo term in the 3-product MFMA is
// ~2^-16 rel -> ~1e-5 abs in h (threshold head-room ~40x).

__global__ __launch_bounds__(256) void prepW_kernel(const float* __restrict__ W1,
        short* __restrict__ WhiT, short* __restrict__ WloT) {
    int idx = blockIdx.x * 256 + threadIdx.x;  // 65536 total
    int k = idx >> 7;
    int n = idx & 127;
    float w = W1[idx];
    unsigned u = f2u(w);
    short h = (short)(u >> 16);
    float hif = u2f(u & 0xffff0000u);
    short l = (short)(f2u(w - hif) >> 16);
    WhiT[(size_t)n * F_IN + k] = h;
    WloT[(size_t)n * F_IN + k] = l;
}

// ---------------- GEMM1: Hs = (x @ W1) * dinv[row]  via split-bf16 MFMA ----------------
// Block: 64 rows x 128 cols, 256 threads = 4 waves; wave w owns cols w*32..+32.
// A staged fp32->hi/lo bf16 in LDS, row stride 40 shorts (80B = 20 dwords,
// coprime-ish with 32 banks -> 8 rows span all banks -> 2-way conflicts, free).
// B fragments loaded straight from pre-transposed WhiT/WloT (L2-hot, 16B/lane).
// mfma_f32_16x16x32_bf16: A lane=row(l&15), k-chunk (l>>4)*8; B lane=col(l&15),
// same k-chunk; C/D col=lane&15, row=(lane>>4)*4+reg (m89-verified layout).

#define LDA 40

__global__ __launch_bounds__(256) void gemm1_mfma(
        const float* __restrict__ X, const short* __restrict__ WhiT,
        const short* __restrict__ WloT, const float* __restrict__ dinv,
        float* __restrict__ Hs, int M) {
    __shared__ short Ahi[64 * LDA];
    __shared__ short Alo[64 * LDA];
    const int tid = threadIdx.x;
    const int lane = tid & 63;
    const int wid = tid >> 6;
    const int m0 = blockIdx.x * 64;
    const int n0 = wid * 32;
    const int l15 = lane & 15;
    const int kc = lane >> 4;

    // staging: thread -> (row tid>>2, 8-float slot tid&3)
    const int sr = tid >> 2;
    const int sc = tid & 3;
    int grow = m0 + sr; if (grow > M - 1) grow = M - 1;
    const float* xp = X + (size_t)grow * F_IN + sc * 8;
    short* ahw = &Ahi[sr * LDA + sc * 8];
    short* alw = &Alo[sr * LDA + sc * 8];

    const short* bhp = WhiT + (size_t)(n0 + l15) * F_IN + kc * 8;
    const short* blp = WloT + (size_t)(n0 + l15) * F_IN + kc * 8;

    f32x4 acc[4][2];
    #pragma unroll
    for (int i = 0; i < 4; ++i)
        #pragma unroll
        for (int j = 0; j < 2; ++j)
            acc[i][j] = (f32x4){0.f, 0.f, 0.f, 0.f};

    for (int k0 = 0; k0 < F_IN; k0 += 32) {
        float4 a0 = *reinterpret_cast<const float4*>(xp + k0);
        float4 a1 = *reinterpret_cast<const float4*>(xp + k0 + 4);
        float av[8] = {a0.x, a0.y, a0.z, a0.w, a1.x, a1.y, a1.z, a1.w};
        short8 vh, vl;
        #pragma unroll
        for (int j = 0; j < 8; ++j) {
            unsigned u = f2u(av[j]);
            vh[j] = (short)(u >> 16);
            float hif = u2f(u & 0xffff0000u);
            vl[j] = (short)(f2u(av[j] - hif) >> 16);
        }
        __syncthreads();  // previous iteration's readers done
        *reinterpret_cast<short8*>(ahw) = vh;
        *reinterpret_cast<short8*>(alw) = vl;
        // B fragments from global (L2-hot), no LDS
        short8 bh0 = *reinterpret_cast<const short8*>(bhp + k0);
        short8 bl0 = *reinterpret_cast<const short8*>(blp + k0);
        short8 bh1 = *reinterpret_cast<const short8*>(bhp + 16 * F_IN + k0);
        short8 bl1 = *reinterpret_cast<const short8*>(blp + 16 * F_IN + k0);
        __syncthreads();  // A tile visible
        #pragma unroll
        for (int mt = 0; mt < 4; ++mt) {
            const short8 ah = *reinterpret_cast<const short8*>(&Ahi[(mt * 16 + l15) * LDA + kc * 8]);
            const short8 al = *reinterpret_cast<const short8*>(&Alo[(mt * 16 + l15) * LDA + kc * 8]);
            acc[mt][0] = __builtin_amdgcn_mfma_f32_16x16x32_bf16(ah, bh0, acc[mt][0], 0, 0, 0);
            acc[mt][0] = __builtin_amdgcn_mfma_f32_16x16x32_bf16(ah, bl0, acc[mt][0], 0, 0, 0);
            acc[mt][0] = __builtin_amdgcn_mfma_f32_16x16x32_bf16(al, bh0, acc[mt][0], 0, 0, 0);
            acc[mt][1] = __builtin_amdgcn_mfma_f32_16x16x32_bf16(ah, bh1, acc[mt][1], 0, 0, 0);
            acc[mt][1] = __builtin_amdgcn_mfma_f32_16x16x32_bf16(ah, bl1, acc[mt][1], 0, 0, 0);
            acc[mt][1] = __builtin_amdgcn_mfma_f32_16x16x32_bf16(al, bh1, acc[mt][1], 0, 0, 0);
        }
    }
    #pragma unroll
    for (int mt = 0; mt < 4; ++mt) {
        #pragma unroll
        for (int r = 0; r < 4; ++r) {
            int row = m0 + mt * 16 + kc * 4 + r;
            if (row < M) {
                float di = dinv[row];
                #pragma unroll
                for (int nt = 0; nt < 2; ++nt) {
                    Hs[(size_t)row * NHID + n0 + nt * 16 + l15] = acc[mt][nt][r] * di;
                }
            }
        }
    }
}

// ---------------- AGG1: Y = relu(dinv[i]*(Hs[i] + sum Hs[src]) + b1) ----------------

__global__ __launch_bounds__(128) void agg1_kernel(const float* __restrict__ Hs,
        const int* __restrict__ row_ptr, const int* __restrict__ col,
        const float* __restrict__ dinv, const float* __restrict__ b1,
        float* __restrict__ Y) {
    const int i = blockIdx.x;
    const int c = threadIdx.x;
    const int beg = row_ptr[i], end = row_ptr[i + 1];
    float acc = Hs[(size_t)i * NHID + c];
    int e = beg;
    for (; e + 4 <= end; e += 4) {
        int s0 = col[e], s1 = col[e + 1], s2 = col[e + 2], s3 = col[e + 3];
        float v0 = Hs[(size_t)s0 * NHID + c];
        float v1 = Hs[(size_t)s1 * NHID + c];
        float v2 = Hs[(size_t)s2 * NHID + c];
        float v3 = Hs[(size_t)s3 * NHID + c];
        acc += (v0 + v1) + (v2 + v3);
    }
    for (; e < end; ++e) acc += Hs[(size_t)col[e] * NHID + c];
    float v = fmaf(acc, dinv[i], b1[c]);
    Y[(size_t)i * NHID + c] = fmaxf(v, 0.0f);
}

// ---------------- GEMM2: H2s = (Y @ W2) * dinv[row]  [N,64] ----------------

__global__ __launch_bounds__(256) void gemm2_kernel(const float* __restrict__ Y,
        const float* __restrict__ W2, const float* __restrict__ dinv,
        float* __restrict__ H2s, int N) {
    __shared__ float Ws[NHID][NCLS];
    __shared__ float Ys[16][NHID];
    const int tid = threadIdx.x;
    const int i0 = blockIdx.x * 16;
    #pragma unroll
    for (int t = 0; t < 8; ++t) {
        int v = tid + t * 256;
        int k = v >> 4;
        int c4 = (v & 15) * 4;
        *reinterpret_cast<float4*>(&Ws[k][c4]) =
            *reinterpret_cast<const float4*>(&W2[(size_t)k * NCLS + c4]);
    }
    #pragma unroll
    for (int t = 0; t < 2; ++t) {
        int v = tid + t * 256;
        int r = v >> 5;
        int c4 = (v & 31) * 4;
        int gr = i0 + r; if (gr > N - 1) gr = N - 1;
        *reinterpret_cast<float4*>(&Ys[r][c4]) =
            *reinterpret_cast<const float4*>(&Y[(size_t)gr * NHID + c4]);
    }
    __syncthreads();
    const int c = tid & 63;
    const int rg = tid >> 6;
    float acc[4] = {0.f, 0.f, 0.f, 0.f};
    #pragma unroll 8
    for (int k = 0; k < NHID; ++k) {
        float w = Ws[k][c];
        #pragma unroll
        for (int j = 0; j < 4; ++j)
            acc[j] = fmaf(Ys[rg * 4 + j][k], w, acc[j]);
    }
    #pragma unroll
    for (int j = 0; j < 4; ++j) {
        int gr = i0 + rg * 4 + j;
        if (gr < N) H2s[(size_t)gr * NCLS + c] = acc[j] * dinv[gr];
    }
}

// ---------------- AGG2 + softmax ----------------

__global__ __launch_bounds__(64) void agg2_kernel(const float* __restrict__ H2s,
        const int* __restrict__ row_ptr, const int* __restrict__ col,
        const float* __restrict__ dinv, const float* __restrict__ b2,
        float* __restrict__ out) {
    const int i = blockIdx.x;
    const int c = threadIdx.x;
    const int beg = row_ptr[i], end = row_ptr[i + 1];
    float acc = H2s[(size_t)i * NCLS + c];
    int e = beg;
    for (; e + 4 <= end; e += 4) {
        int s0 = col[e], s1 = col[e + 1], s2 = col[e + 2], s3 = col[e + 3];
        float v0 = H2s[(size_t)s0 * NCLS + c];
        float v1 = H2s[(size_t)s1 * NCLS + c];
        float v2 = H2s[(size_t)s2 * NCLS + c];
        float v3 = H2s[(size_t)s3 * NCLS + c];
        acc += (v0 + v1) + (v2 + v3);
    }
    for (; e < end; ++e) acc += H2s[(size_t)col[e] * NCLS + c];
    float v = fmaf(acc, dinv[i], b2[c]);
    float m = v;
    #pragma unroll
    for (int d = 32; d >= 1; d >>= 1) m = fmaxf(m, __shfl_xor(m, d));
    float ex = __expf(v - m);
    float sum = ex;
    #pragma unroll
    for (int d = 32; d >= 1; d >>= 1) sum += __shfl_xor(sum, d);
    out[(size_t)i * NCLS + c] = ex / sum;
}

// ---------------- launch ----------------

extern "C" void kernel_launch(void* const* d_in, const int* in_sizes, int n_in,
                              void* d_out, int out_size, void* d_ws, size_t ws_size,
                              hipStream_t stream) {
    const float* x  = (const float*)d_in[0];
    const int*   ei = (const int*)d_in[1];
    const float* W1 = (const float*)d_in[2];
    const float* b1 = (const float*)d_in[3];
    const float* W2 = (const float*)d_in[4];
    const float* b2 = (const float*)d_in[5];
    const int N = in_sizes[0] / F_IN;
    const int E = in_sizes[1] / 2;
    const int* src = ei;
    const int* dst = ei + E;
    float* out = (float*)d_out;

    const int Npad = (N + 63) & ~63;
    const int Epad = (E + 63) & ~63;
    int*   cnt     = (int*)d_ws;               // Npad
    int*   cursor  = cnt + Npad;               // Npad
    int*   row_ptr = cursor + Npad;            // Npad (>= N+1)
    float* dinv    = (float*)(row_ptr + Npad); // Npad
    int*   col     = (int*)(dinv + Npad);      // Epad
    float* Hs      = (float*)(col + Epad);     // Npad*128
    float* Y       = Hs + (size_t)Npad * NHID; // Npad*128
    float* H2s     = Hs;                       // reuse (Hs dead after agg1)
    // WhiT/WloT (128KB each) overlay the Y region: written by prepW, consumed
    // by gemm1_mfma, dead before agg1 writes Y. Zero extra workspace.
    short* WhiT    = (short*)Y;                // 65536 shorts
    short* WloT    = WhiT + (size_t)F_IN * NHID;

    hipMemsetAsync(cnt, 0, (size_t)2 * Npad * sizeof(int), stream);
    count_kernel<<<(E + 255) / 256, 256, 0, stream>>>(dst, cnt, E);
    scan_kernel<<<1, 1024, 0, stream>>>(cnt, row_ptr, dinv, N);
    fill_kernel<<<(E + 255) / 256, 256, 0, stream>>>(src, dst, row_ptr, cursor, col, E);
    prepW_kernel<<<(F_IN * NHID) / 256, 256, 0, stream>>>(W1, WhiT, WloT);
    gemm1_mfma<<<(N + 63) / 64, 256, 0, stream>>>(x, WhiT, WloT, dinv, Hs, N);
    agg1_kernel<<<N, 128, 0, stream>>>(Hs, row_ptr, col, dinv, b1, Y);
    gemm2_kernel<<<(N + 15) / 16, 256, 0, stream>>>(Y, W2, dinv, H2s, N);
    agg2_kernel<<<N, 64, 0, stream>>>(H2s, row_ptr, col, dinv, b2, out);
}

// Round 3
// 318.138 us; speedup vs baseline: 1.6035x; 1.4210x over previous
//
#include <hip/hip_runtime.h>
#include <hip/hip_bf16.h>
#include <hip/hip_fp16.h>

// ---------------------------------------------------------------------------
// GCN 2-layer inference:
//   h1 = relu( D^-1/2 (A+I) D^-1/2 (x @ W1) + b1 )
//   out = softmax( D^-1/2 (A+I) D^-1/2 (h1 @ W2) + b2 )
//
// memset -> count -> scan1/2/3 (multi-block) -> fill(CSR) -> prepW ->
// gemm1_mfma (split-bf16, epilogue *dinv -> fp16 Hs) -> agg1 (fp16 gather,
// fp32 accum, +b1, relu) -> gemm2 (epilogue *dinv -> fp16 H2s) ->
// agg2 (fp16 gather, +b2, softmax).
// fp16 intermediates: |h*dinv| <= ~1, round-off 2^-12 -> final absmax ~2e-4,
// under the 4.15e-4 threshold; gather traffic halves (the round-2 bottleneck).
// ---------------------------------------------------------------------------

#define F_IN 512
#define NHID 128
#define NCLS 64

typedef __attribute__((ext_vector_type(8))) short short8;
typedef __attribute__((ext_vector_type(4))) float f32x4;

__device__ __forceinline__ unsigned f2u(float f) { union { float f; unsigned u; } v; v.f = f; return v.u; }
__device__ __forceinline__ float u2f(unsigned u) { union { unsigned u; float f; } v; v.u = u; return v.f; }

// ---------------- CSR build ----------------

__global__ void count_kernel(const int* __restrict__ dst, int* __restrict__ cnt, int E) {
    int e = blockIdx.x * blockDim.x + threadIdx.x;
    if (e < E) atomicAdd(&cnt[dst[e]], 1);
}

// scan1: each 256-thread block scans 1024 elements (4/thread), writes
// block-local exclusive prefix to row_ptr, block total to bsum, dinv.
__global__ __launch_bounds__(256) void scan1_kernel(const int* __restrict__ cnt,
        int* __restrict__ row_ptr, float* __restrict__ dinv,
        int* __restrict__ bsum, int N) {
    __shared__ int wsum[4];
    const int tid = threadIdx.x;
    const int lane = tid & 63, wid = tid >> 6;
    const int base = blockIdx.x * 1024 + tid * 4;
    int4 v = {0, 0, 0, 0};
    if (base + 3 < N) {
        v = *reinterpret_cast<const int4*>(&cnt[base]);
    } else {
        if (base + 0 < N) v.x = cnt[base + 0];
        if (base + 1 < N) v.y = cnt[base + 1];
        if (base + 2 < N) v.z = cnt[base + 2];
        if (base + 3 < N) v.w = cnt[base + 3];
    }
    if (base + 0 < N) dinv[base + 0] = rsqrtf((float)v.x + 1.0f);
    if (base + 1 < N) dinv[base + 1] = rsqrtf((float)v.y + 1.0f);
    if (base + 2 < N) dinv[base + 2] = rsqrtf((float)v.z + 1.0f);
    if (base + 3 < N) dinv[base + 3] = rsqrtf((float)v.w + 1.0f);
    const int tsum = v.x + v.y + v.z + v.w;
    int s = tsum;
    #pragma unroll
    for (int d = 1; d < 64; d <<= 1) {
        int t = __shfl_up(s, d);
        if (lane >= d) s += t;
    }
    if (lane == 63) wsum[wid] = s;
    __syncthreads();
    int woff = 0;
    for (int w = 0; w < wid; ++w) woff += wsum[w];
    const int excl = woff + s - tsum;
    if (base + 0 < N) row_ptr[base + 0] = excl;
    if (base + 1 < N) row_ptr[base + 1] = excl + v.x;
    if (base + 2 < N) row_ptr[base + 2] = excl + v.x + v.y;
    if (base + 3 < N) row_ptr[base + 3] = excl + v.x + v.y + v.z;
    if (tid == 255) bsum[blockIdx.x] = excl + tsum;
}

// scan2: one wave scans the (<=64) block sums into exclusive offsets.
__global__ __launch_bounds__(64) void scan2_kernel(const int* __restrict__ bsum,
        int* __restrict__ boff, int* __restrict__ row_ptr, int nb, int N) {
    const int lane = threadIdx.x;
    int v = (lane < nb) ? bsum[lane] : 0;
    int s = v;
    #pragma unroll
    for (int d = 1; d < 64; d <<= 1) {
        int t = __shfl_up(s, d);
        if (lane >= d) s += t;
    }
    if (lane < nb) boff[lane] = s - v;
    if (lane == 63) row_ptr[N] = s;
}

__global__ void scan3_kernel(int* __restrict__ row_ptr, const int* __restrict__ boff, int N) {
    int i = blockIdx.x * blockDim.x + threadIdx.x;
    if (i < N) row_ptr[i] += boff[i >> 10];
}

__global__ void fill_kernel(const int* __restrict__ src, const int* __restrict__ dst,
        const int* __restrict__ row_ptr, int* __restrict__ cursor,
        int* __restrict__ col, int E) {
    int e = blockIdx.x * blockDim.x + threadIdx.x;
    if (e < E) {
        int d = dst[e];
        int pos = row_ptr[d] + atomicAdd(&cursor[d], 1);
        col[pos] = src[e];
    }
}

// ---------------- prepW: W1 [512][128] f32 -> WhiT/WloT [128][512] bf16 ----------------

__global__ __launch_bounds__(256) void prepW_kernel(const float* __restrict__ W1,
        short* __restrict__ WhiT, short* __restrict__ WloT) {
    int idx = blockIdx.x * 256 + threadIdx.x;
    int k = idx >> 7;
    int n = idx & 127;
    float w = W1[idx];
    unsigned u = f2u(w);
    short h = (short)(u >> 16);
    float hif = u2f(u & 0xffff0000u);
    short l = (short)(f2u(w - hif) >> 16);
    WhiT[(size_t)n * F_IN + k] = h;
    WloT[(size_t)n * F_IN + k] = l;
}

// ---------------- GEMM1: Hs16 = fp16((x @ W1) * dinv[row]) via split-bf16 MFMA ----------------

#define LDA 40

__global__ __launch_bounds__(256) void gemm1_mfma(
        const float* __restrict__ X, const short* __restrict__ WhiT,
        const short* __restrict__ WloT, const float* __restrict__ dinv,
        __half* __restrict__ Hs16, int M) {
    __shared__ short Ahi[64 * LDA];
    __shared__ short Alo[64 * LDA];
    const int tid = threadIdx.x;
    const int lane = tid & 63;
    const int wid = tid >> 6;
    const int m0 = blockIdx.x * 64;
    const int n0 = wid * 32;
    const int l15 = lane & 15;
    const int kc = lane >> 4;

    const int sr = tid >> 2;
    const int sc = tid & 3;
    int grow = m0 + sr; if (grow > M - 1) grow = M - 1;
    const float* xp = X + (size_t)grow * F_IN + sc * 8;
    short* ahw = &Ahi[sr * LDA + sc * 8];
    short* alw = &Alo[sr * LDA + sc * 8];

    const short* bhp = WhiT + (size_t)(n0 + l15) * F_IN + kc * 8;
    const short* blp = WloT + (size_t)(n0 + l15) * F_IN + kc * 8;

    f32x4 acc[4][2];
    #pragma unroll
    for (int i = 0; i < 4; ++i)
        #pragma unroll
        for (int j = 0; j < 2; ++j)
            acc[i][j] = (f32x4){0.f, 0.f, 0.f, 0.f};

    for (int k0 = 0; k0 < F_IN; k0 += 32) {
        float4 a0 = *reinterpret_cast<const float4*>(xp + k0);
        float4 a1 = *reinterpret_cast<const float4*>(xp + k0 + 4);
        float av[8] = {a0.x, a0.y, a0.z, a0.w, a1.x, a1.y, a1.z, a1.w};
        short8 vh, vl;
        #pragma unroll
        for (int j = 0; j < 8; ++j) {
            unsigned u = f2u(av[j]);
            vh[j] = (short)(u >> 16);
            float hif = u2f(u & 0xffff0000u);
            vl[j] = (short)(f2u(av[j] - hif) >> 16);
        }
        __syncthreads();
        *reinterpret_cast<short8*>(ahw) = vh;
        *reinterpret_cast<short8*>(alw) = vl;
        short8 bh0 = *reinterpret_cast<const short8*>(bhp + k0);
        short8 bl0 = *reinterpret_cast<const short8*>(blp + k0);
        short8 bh1 = *reinterpret_cast<const short8*>(bhp + 16 * F_IN + k0);
        short8 bl1 = *reinterpret_cast<const short8*>(blp + 16 * F_IN + k0);
        __syncthreads();
        #pragma unroll
        for (int mt = 0; mt < 4; ++mt) {
            const short8 ah = *reinterpret_cast<const short8*>(&Ahi[(mt * 16 + l15) * LDA + kc * 8]);
            const short8 al = *reinterpret_cast<const short8*>(&Alo[(mt * 16 + l15) * LDA + kc * 8]);
            acc[mt][0] = __builtin_amdgcn_mfma_f32_16x16x32_bf16(ah, bh0, acc[mt][0], 0, 0, 0);
            acc[mt][0] = __builtin_amdgcn_mfma_f32_16x16x32_bf16(ah, bl0, acc[mt][0], 0, 0, 0);
            acc[mt][0] = __builtin_amdgcn_mfma_f32_16x16x32_bf16(al, bh0, acc[mt][0], 0, 0, 0);
            acc[mt][1] = __builtin_amdgcn_mfma_f32_16x16x32_bf16(ah, bh1, acc[mt][1], 0, 0, 0);
            acc[mt][1] = __builtin_amdgcn_mfma_f32_16x16x32_bf16(ah, bl1, acc[mt][1], 0, 0, 0);
            acc[mt][1] = __builtin_amdgcn_mfma_f32_16x16x32_bf16(al, bh1, acc[mt][1], 0, 0, 0);
        }
    }
    #pragma unroll
    for (int mt = 0; mt < 4; ++mt) {
        #pragma unroll
        for (int r = 0; r < 4; ++r) {
            int row = m0 + mt * 16 + kc * 4 + r;
            if (row < M) {
                float di = dinv[row];
                #pragma unroll
                for (int nt = 0; nt < 2; ++nt) {
                    Hs16[(size_t)row * NHID + n0 + nt * 16 + l15] =
                        __float2half(acc[mt][nt][r] * di);
                }
            }
        }
    }
}

// ---------------- AGG1: Y = relu(dinv[i]*(Hs[i] + sum Hs[src]) + b1) ----------------
// One wave per node; thread owns a half2 column pair (4B/lane coalesced).

__global__ __launch_bounds__(64) void agg1_kernel(const __half2* __restrict__ Hs,
        const int* __restrict__ row_ptr, const int* __restrict__ col,
        const float* __restrict__ dinv, const float* __restrict__ b1,
        float* __restrict__ Y) {
    const int i = blockIdx.x;
    const int c = threadIdx.x;           // col-pair 0..63
    const int beg = row_ptr[i], end = row_ptr[i + 1];
    float2 f = __half22float2(Hs[(size_t)i * 64 + c]);
    float ax = f.x, ay = f.y;
    int e = beg;
    for (; e + 8 <= end; e += 8) {
        float2 v[8];
        #pragma unroll
        for (int j = 0; j < 8; ++j) {
            int s = col[e + j];
            v[j] = __half22float2(Hs[(size_t)s * 64 + c]);
        }
        #pragma unroll
        for (int j = 0; j < 8; ++j) { ax += v[j].x; ay += v[j].y; }
    }
    for (; e < end; ++e) {
        float2 v = __half22float2(Hs[(size_t)col[e] * 64 + c]);
        ax += v.x; ay += v.y;
    }
    const float di = dinv[i];
    const float2 bb = reinterpret_cast<const float2*>(b1)[c];
    float2 o;
    o.x = fmaxf(fmaf(ax, di, bb.x), 0.0f);
    o.y = fmaxf(fmaf(ay, di, bb.y), 0.0f);
    *reinterpret_cast<float2*>(&Y[(size_t)i * NHID + 2 * c]) = o;
}

// ---------------- GEMM2: H2s16 = fp16((Y @ W2) * dinv[row])  [N,64] ----------------

__global__ __launch_bounds__(256) void gemm2_kernel(const float* __restrict__ Y,
        const float* __restrict__ W2, const float* __restrict__ dinv,
        __half* __restrict__ H2s16, int N) {
    __shared__ float Ws[NHID][NCLS];
    __shared__ float Ys[16][NHID];
    const int tid = threadIdx.x;
    const int i0 = blockIdx.x * 16;
    #pragma unroll
    for (int t = 0; t < 8; ++t) {
        int v = tid + t * 256;
        int k = v >> 4;
        int c4 = (v & 15) * 4;
        *reinterpret_cast<float4*>(&Ws[k][c4]) =
            *reinterpret_cast<const float4*>(&W2[(size_t)k * NCLS + c4]);
    }
    #pragma unroll
    for (int t = 0; t < 2; ++t) {
        int v = tid + t * 256;
        int r = v >> 5;
        int c4 = (v & 31) * 4;
        int gr = i0 + r; if (gr > N - 1) gr = N - 1;
        *reinterpret_cast<float4*>(&Ys[r][c4]) =
            *reinterpret_cast<const float4*>(&Y[(size_t)gr * NHID + c4]);
    }
    __syncthreads();
    const int c = tid & 63;
    const int rg = tid >> 6;
    float acc[4] = {0.f, 0.f, 0.f, 0.f};
    #pragma unroll 8
    for (int k = 0; k < NHID; ++k) {
        float w = Ws[k][c];
        #pragma unroll
        for (int j = 0; j < 4; ++j)
            acc[j] = fmaf(Ys[rg * 4 + j][k], w, acc[j]);
    }
    #pragma unroll
    for (int j = 0; j < 4; ++j) {
        int gr = i0 + rg * 4 + j;
        if (gr < N) H2s16[(size_t)gr * NCLS + c] = __float2half(acc[j] * dinv[gr]);
    }
}

// ---------------- AGG2 + softmax: two nodes per wave (lanes 0-31 / 32-63) ----------------

__global__ __launch_bounds__(64) void agg2_kernel(const __half2* __restrict__ H2,
        const int* __restrict__ row_ptr, const int* __restrict__ col,
        const float* __restrict__ dinv, const float* __restrict__ b2,
        float* __restrict__ out, int N) {
    const int lane = threadIdx.x;
    const int node = blockIdx.x * 2 + (lane >> 5);
    const int c = lane & 31;             // col-pair 0..31
    if (node >= N) return;
    const int beg = row_ptr[node], end = row_ptr[node + 1];
    float2 f = __half22float2(H2[(size_t)node * 32 + c]);
    float ax = f.x, ay = f.y;
    int e = beg;
    for (; e + 8 <= end; e += 8) {
        float2 v[8];
        #pragma unroll
        for (int j = 0; j < 8; ++j) {
            int s = col[e + j];
            v[j] = __half22float2(H2[(size_t)s * 32 + c]);
        }
        #pragma unroll
        for (int j = 0; j < 8; ++j) { ax += v[j].x; ay += v[j].y; }
    }
    for (; e < end; ++e) {
        float2 v = __half22float2(H2[(size_t)col[e] * 32 + c]);
        ax += v.x; ay += v.y;
    }
    const float di = dinv[node];
    const float2 bb = reinterpret_cast<const float2*>(b2)[c];
    float vx = fmaf(ax, di, bb.x);
    float vy = fmaf(ay, di, bb.y);
    float m = fmaxf(vx, vy);
    #pragma unroll
    for (int d = 16; d >= 1; d >>= 1) m = fmaxf(m, __shfl_xor(m, d));
    float ex = __expf(vx - m), ey = __expf(vy - m);
    float sum = ex + ey;
    #pragma unroll
    for (int d = 16; d >= 1; d >>= 1) sum += __shfl_xor(sum, d);
    float2 o = {ex / sum, ey / sum};
    reinterpret_cast<float2*>(out)[(size_t)node * 32 + c] = o;
}

// ---------------- launch ----------------

extern "C" void kernel_launch(void* const* d_in, const int* in_sizes, int n_in,
                              void* d_out, int out_size, void* d_ws, size_t ws_size,
                              hipStream_t stream) {
    const float* x  = (const float*)d_in[0];
    const int*   ei = (const int*)d_in[1];
    const float* W1 = (const float*)d_in[2];
    const float* b1 = (const float*)d_in[3];
    const float* W2 = (const float*)d_in[4];
    const float* b2 = (const float*)d_in[5];
    const int N = in_sizes[0] / F_IN;
    const int E = in_sizes[1] / 2;
    const int* src = ei;
    const int* dst = ei + E;
    float* out = (float*)d_out;

    const int Npad = (N + 63) & ~63;
    const int Epad = (E + 63) & ~63;
    int*    cnt     = (int*)d_ws;                 // Npad
    int*    cursor  = cnt + Npad;                 // Npad
    int*    row_ptr = cursor + Npad;              // Npad (>= N+1)
    float*  dinv    = (float*)(row_ptr + Npad);   // Npad
    int*    col     = (int*)(dinv + Npad);        // Epad
    int*    bsum    = col + Epad;                 // 64
    int*    boff    = bsum + 64;                  // 64
    __half* Hs16    = (__half*)(boff + 64);       // Npad*128 halfs (12.8MB)
    float*  Y       = (float*)(Hs16 + (size_t)Npad * NHID);  // Npad*128 f32
    __half* H2s16   = Hs16;                       // reuse (Hs dead after agg1)
    short*  WhiT    = (short*)Y;                  // overlay Y: dead before agg1 writes
    short*  WloT    = WhiT + (size_t)F_IN * NHID;

    const int nb = (N + 1023) / 1024;

    hipMemsetAsync(cnt, 0, (size_t)2 * Npad * sizeof(int), stream);
    count_kernel<<<(E + 255) / 256, 256, 0, stream>>>(dst, cnt, E);
    scan1_kernel<<<nb, 256, 0, stream>>>(cnt, row_ptr, dinv, bsum, N);
    scan2_kernel<<<1, 64, 0, stream>>>(bsum, boff, row_ptr, nb, N);
    scan3_kernel<<<(N + 255) / 256, 256, 0, stream>>>(row_ptr, boff, N);
    fill_kernel<<<(E + 255) / 256, 256, 0, stream>>>(src, dst, row_ptr, cursor, col, E);
    prepW_kernel<<<(F_IN * NHID) / 256, 256, 0, stream>>>(W1, WhiT, WloT);
    gemm1_mfma<<<(N + 63) / 64, 256, 0, stream>>>(x, WhiT, WloT, dinv, Hs16, N);
    agg1_kernel<<<N, 64, 0, stream>>>((const __half2*)Hs16, row_ptr, col, dinv, b1, Y);
    gemm2_kernel<<<(N + 15) / 16, 256, 0, stream>>>(Y, W2, dinv, H2s16, N);
    agg2_kernel<<<(N + 1) / 2, 64, 0, stream>>>((const __half2*)H2s16, row_ptr, col, dinv, b2, out, N);
}

// Round 4
// 298.154 us; speedup vs baseline: 1.7110x; 1.0670x over previous
//
#include <hip/hip_runtime.h>
#include <hip/hip_bf16.h>
#include <hip/hip_fp16.h>

// ---------------------------------------------------------------------------
// GCN 2-layer inference:
//   h1 = relu( D^-1/2 (A+I) D^-1/2 (x @ W1) + b1 )
//   out = softmax( D^-1/2 (A+I) D^-1/2 (h1 @ W2) + b2 )
//
// memset -> count -> scan1/2/3 -> bin (LDS counting-sort by dst-bucket,
// dense run writes) -> fill_b (bucket-local CSR placement) -> prepW ->
// gemm1_mfma (split-bf16 MFMA, *dinv -> fp16 Hs) -> agg1 (fp16 gather) ->
// gemm2 (*dinv -> fp16 H2s) -> agg2 (+softmax).
// Binning replaces the random 4B col scatter (101MB writeback amplification,
// 95us) with dense 8B-pair runs + bucket-local writes (~26MB total).
// ---------------------------------------------------------------------------

#define F_IN 512
#define NHID 128
#define NCLS 64
#define BSHIFT 8           // 256 nodes per bucket
#define CHUNK 4096         // edges per bin block

typedef __attribute__((ext_vector_type(8))) short short8;
typedef __attribute__((ext_vector_type(4))) float f32x4;

__device__ __forceinline__ unsigned f2u(float f) { union { float f; unsigned u; } v; v.f = f; return v.u; }
__device__ __forceinline__ float u2f(unsigned u) { union { unsigned u; float f; } v; v.u = u; return v.f; }

// ---------------- degree count ----------------

__global__ void count_kernel(const int* __restrict__ dst, int* __restrict__ cnt, int E) {
    int e = blockIdx.x * blockDim.x + threadIdx.x;
    if (e < E) atomicAdd(&cnt[dst[e]], 1);
}

// ---------------- row_ptr scan ----------------

__global__ __launch_bounds__(256) void scan1_kernel(const int* __restrict__ cnt,
        int* __restrict__ row_ptr, float* __restrict__ dinv,
        int* __restrict__ bsum, int N) {
    __shared__ int wsum[4];
    const int tid = threadIdx.x;
    const int lane = tid & 63, wid = tid >> 6;
    const int base = blockIdx.x * 1024 + tid * 4;
    int4 v = {0, 0, 0, 0};
    if (base + 3 < N) {
        v = *reinterpret_cast<const int4*>(&cnt[base]);
    } else {
        if (base + 0 < N) v.x = cnt[base + 0];
        if (base + 1 < N) v.y = cnt[base + 1];
        if (base + 2 < N) v.z = cnt[base + 2];
        if (base + 3 < N) v.w = cnt[base + 3];
    }
    if (base + 0 < N) dinv[base + 0] = rsqrtf((float)v.x + 1.0f);
    if (base + 1 < N) dinv[base + 1] = rsqrtf((float)v.y + 1.0f);
    if (base + 2 < N) dinv[base + 2] = rsqrtf((float)v.z + 1.0f);
    if (base + 3 < N) dinv[base + 3] = rsqrtf((float)v.w + 1.0f);
    const int tsum = v.x + v.y + v.z + v.w;
    int s = tsum;
    #pragma unroll
    for (int d = 1; d < 64; d <<= 1) {
        int t = __shfl_up(s, d);
        if (lane >= d) s += t;
    }
    if (lane == 63) wsum[wid] = s;
    __syncthreads();
    int woff = 0;
    for (int w = 0; w < wid; ++w) woff += wsum[w];
    const int excl = woff + s - tsum;
    if (base + 0 < N) row_ptr[base + 0] = excl;
    if (base + 1 < N) row_ptr[base + 1] = excl + v.x;
    if (base + 2 < N) row_ptr[base + 2] = excl + v.x + v.y;
    if (base + 3 < N) row_ptr[base + 3] = excl + v.x + v.y + v.z;
    if (tid == 255) bsum[blockIdx.x] = excl + tsum;
}

__global__ __launch_bounds__(64) void scan2_kernel(const int* __restrict__ bsum,
        int* __restrict__ boff, int* __restrict__ row_ptr, int nb, int N) {
    const int lane = threadIdx.x;
    int v = (lane < nb) ? bsum[lane] : 0;
    int s = v;
    #pragma unroll
    for (int d = 1; d < 64; d <<= 1) {
        int t = __shfl_up(s, d);
        if (lane >= d) s += t;
    }
    if (lane < nb) boff[lane] = s - v;
    if (lane == 63) row_ptr[N] = s;
}

__global__ void scan3_kernel(int* __restrict__ row_ptr, const int* __restrict__ boff, int N) {
    int i = blockIdx.x * blockDim.x + threadIdx.x;
    if (i < N) row_ptr[i] += boff[i >> 10];
}

// ---------------- binning: LDS counting-sort of 4096-edge chunks by bucket ----------------

__global__ __launch_bounds__(256) void bin_kernel(const int* __restrict__ src,
        const int* __restrict__ dst, int2* __restrict__ pairs,
        int* __restrict__ bcur, int E, int cap) {
    __shared__ int lcnt[256];
    __shared__ int lscan[256];
    __shared__ int gbase[256];
    __shared__ int wsum[4];
    __shared__ int2 stage[CHUNK];
    const int t = threadIdx.x;
    const int lane = t & 63, wid = t >> 6;
    const int e0 = blockIdx.x * CHUNK;
    const int n = min(CHUNK, E - e0);

    lcnt[t] = 0;
    __syncthreads();
    for (int i = t; i < n; i += 256)
        atomicAdd(&lcnt[dst[e0 + i] >> BSHIFT], 1);
    __syncthreads();
    // block exclusive scan of lcnt (256 entries, 1/thread)
    const int v = lcnt[t];
    int s = v;
    #pragma unroll
    for (int d = 1; d < 64; d <<= 1) {
        int tt = __shfl_up(s, d);
        if (lane >= d) s += tt;
    }
    if (lane == 63) wsum[wid] = s;
    __syncthreads();
    int woff = 0;
    for (int w = 0; w < wid; ++w) woff += wsum[w];
    lscan[t] = woff + s - v;
    gbase[t] = v ? atomicAdd(&bcur[t], v) : 0;
    lcnt[t] = 0;
    __syncthreads();
    // place into stage, sorted by bucket
    for (int i = t; i < n; i += 256) {
        int d = dst[e0 + i], sc = src[e0 + i];
        int b = d >> BSHIFT;
        int p = atomicAdd(&lcnt[b], 1);
        stage[lscan[b] + p] = make_int2(d, sc);
    }
    __syncthreads();
    // dense run writes: consecutive i within a run -> consecutive addresses
    for (int i = t; i < n; i += 256) {
        int2 pr = stage[i];
        int b = pr.x >> BSHIFT;
        int addr = b * cap + gbase[b] + (i - lscan[b]);
        if (gbase[b] + (i - lscan[b]) < cap) pairs[addr] = pr;
    }
}

// ---------------- CSR placement: bucket-local col writes ----------------

__global__ __launch_bounds__(256) void fill_b_kernel(const int2* __restrict__ pairs,
        const int* __restrict__ bcur, const int* __restrict__ row_ptr,
        int* __restrict__ cursor, int* __restrict__ col, int cap) {
    const int b = blockIdx.x >> 2;
    const int q = blockIdx.x & 3;
    const int t = threadIdx.x;
    const int cnt = min(bcur[b], cap);
    const int per = (cnt + 3) >> 2;
    const int lo = q * per;
    const int hi = min(cnt, lo + per);
    for (int i = lo + t; i < hi; i += 256) {
        int2 pr = pairs[(size_t)b * cap + i];
        int pos = row_ptr[pr.x] + atomicAdd(&cursor[pr.x], 1);
        col[pos] = pr.y;
    }
}

// ---------------- prepW: W1 [512][128] f32 -> WhiT/WloT [128][512] bf16 ----------------

__global__ __launch_bounds__(256) void prepW_kernel(const float* __restrict__ W1,
        short* __restrict__ WhiT, short* __restrict__ WloT) {
    int idx = blockIdx.x * 256 + threadIdx.x;
    int k = idx >> 7;
    int n = idx & 127;
    float w = W1[idx];
    unsigned u = f2u(w);
    short h = (short)(u >> 16);
    float hif = u2f(u & 0xffff0000u);
    short l = (short)(f2u(w - hif) >> 16);
    WhiT[(size_t)n * F_IN + k] = h;
    WloT[(size_t)n * F_IN + k] = l;
}

// ---------------- GEMM1: Hs16 = fp16((x @ W1) * dinv[row]) via split-bf16 MFMA ----------------

#define LDA 40

__global__ __launch_bounds__(256) void gemm1_mfma(
        const float* __restrict__ X, const short* __restrict__ WhiT,
        const short* __restrict__ WloT, const float* __restrict__ dinv,
        __half* __restrict__ Hs16, int M) {
    __shared__ short Ahi[64 * LDA];
    __shared__ short Alo[64 * LDA];
    const int tid = threadIdx.x;
    const int lane = tid & 63;
    const int wid = tid >> 6;
    const int m0 = blockIdx.x * 64;
    const int n0 = wid * 32;
    const int l15 = lane & 15;
    const int kc = lane >> 4;

    const int sr = tid >> 2;
    const int sc = tid & 3;
    int grow = m0 + sr; if (grow > M - 1) grow = M - 1;
    const float* xp = X + (size_t)grow * F_IN + sc * 8;
    short* ahw = &Ahi[sr * LDA + sc * 8];
    short* alw = &Alo[sr * LDA + sc * 8];

    const short* bhp = WhiT + (size_t)(n0 + l15) * F_IN + kc * 8;
    const short* blp = WloT + (size_t)(n0 + l15) * F_IN + kc * 8;

    f32x4 acc[4][2];
    #pragma unroll
    for (int i = 0; i < 4; ++i)
        #pragma unroll
        for (int j = 0; j < 2; ++j)
            acc[i][j] = (f32x4){0.f, 0.f, 0.f, 0.f};

    for (int k0 = 0; k0 < F_IN; k0 += 32) {
        float4 a0 = *reinterpret_cast<const float4*>(xp + k0);
        float4 a1 = *reinterpret_cast<const float4*>(xp + k0 + 4);
        float av[8] = {a0.x, a0.y, a0.z, a0.w, a1.x, a1.y, a1.z, a1.w};
        short8 vh, vl;
        #pragma unroll
        for (int j = 0; j < 8; ++j) {
            unsigned u = f2u(av[j]);
            vh[j] = (short)(u >> 16);
            float hif = u2f(u & 0xffff0000u);
            vl[j] = (short)(f2u(av[j] - hif) >> 16);
        }
        __syncthreads();
        *reinterpret_cast<short8*>(ahw) = vh;
        *reinterpret_cast<short8*>(alw) = vl;
        short8 bh0 = *reinterpret_cast<const short8*>(bhp + k0);
        short8 bl0 = *reinterpret_cast<const short8*>(blp + k0);
        short8 bh1 = *reinterpret_cast<const short8*>(bhp + 16 * F_IN + k0);
        short8 bl1 = *reinterpret_cast<const short8*>(blp + 16 * F_IN + k0);
        __syncthreads();
        #pragma unroll
        for (int mt = 0; mt < 4; ++mt) {
            const short8 ah = *reinterpret_cast<const short8*>(&Ahi[(mt * 16 + l15) * LDA + kc * 8]);
            const short8 al = *reinterpret_cast<const short8*>(&Alo[(mt * 16 + l15) * LDA + kc * 8]);
            acc[mt][0] = __builtin_amdgcn_mfma_f32_16x16x32_bf16(ah, bh0, acc[mt][0], 0, 0, 0);
            acc[mt][0] = __builtin_amdgcn_mfma_f32_16x16x32_bf16(ah, bl0, acc[mt][0], 0, 0, 0);
            acc[mt][0] = __builtin_amdgcn_mfma_f32_16x16x32_bf16(al, bh0, acc[mt][0], 0, 0, 0);
            acc[mt][1] = __builtin_amdgcn_mfma_f32_16x16x32_bf16(ah, bh1, acc[mt][1], 0, 0, 0);
            acc[mt][1] = __builtin_amdgcn_mfma_f32_16x16x32_bf16(ah, bl1, acc[mt][1], 0, 0, 0);
            acc[mt][1] = __builtin_amdgcn_mfma_f32_16x16x32_bf16(al, bh1, acc[mt][1], 0, 0, 0);
        }
    }
    #pragma unroll
    for (int mt = 0; mt < 4; ++mt) {
        #pragma unroll
        for (int r = 0; r < 4; ++r) {
            int row = m0 + mt * 16 + kc * 4 + r;
            if (row < M) {
                float di = dinv[row];
                #pragma unroll
                for (int nt = 0; nt < 2; ++nt) {
                    Hs16[(size_t)row * NHID + n0 + nt * 16 + l15] =
                        __float2half(acc[mt][nt][r] * di);
                }
            }
        }
    }
}

// ---------------- AGG1: Y = relu(dinv[i]*(Hs[i] + sum Hs[src]) + b1) ----------------

__global__ __launch_bounds__(64) void agg1_kernel(const __half2* __restrict__ Hs,
        const int* __restrict__ row_ptr, const int* __restrict__ col,
        const float* __restrict__ dinv, const float* __restrict__ b1,
        float* __restrict__ Y) {
    const int i = blockIdx.x;
    const int c = threadIdx.x;           // col-pair 0..63
    const int beg = row_ptr[i], end = row_ptr[i + 1];
    float2 f = __half22float2(Hs[(size_t)i * 64 + c]);
    float ax = f.x, ay = f.y;
    int e = beg;
    for (; e + 8 <= end; e += 8) {
        float2 v[8];
        #pragma unroll
        for (int j = 0; j < 8; ++j) {
            int s = col[e + j];
            v[j] = __half22float2(Hs[(size_t)s * 64 + c]);
        }
        #pragma unroll
        for (int j = 0; j < 8; ++j) { ax += v[j].x; ay += v[j].y; }
    }
    for (; e < end; ++e) {
        float2 v = __half22float2(Hs[(size_t)col[e] * 64 + c]);
        ax += v.x; ay += v.y;
    }
    const float di = dinv[i];
    const float2 bb = reinterpret_cast<const float2*>(b1)[c];
    float2 o;
    o.x = fmaxf(fmaf(ax, di, bb.x), 0.0f);
    o.y = fmaxf(fmaf(ay, di, bb.y), 0.0f);
    *reinterpret_cast<float2*>(&Y[(size_t)i * NHID + 2 * c]) = o;
}

// ---------------- GEMM2: H2s16 = fp16((Y @ W2) * dinv[row])  [N,64] ----------------

__global__ __launch_bounds__(256) void gemm2_kernel(const float* __restrict__ Y,
        const float* __restrict__ W2, const float* __restrict__ dinv,
        __half* __restrict__ H2s16, int N) {
    __shared__ float Ws[NHID][NCLS];
    __shared__ float Ys[16][NHID];
    const int tid = threadIdx.x;
    const int i0 = blockIdx.x * 16;
    #pragma unroll
    for (int t = 0; t < 8; ++t) {
        int v = tid + t * 256;
        int k = v >> 4;
        int c4 = (v & 15) * 4;
        *reinterpret_cast<float4*>(&Ws[k][c4]) =
            *reinterpret_cast<const float4*>(&W2[(size_t)k * NCLS + c4]);
    }
    #pragma unroll
    for (int t = 0; t < 2; ++t) {
        int v = tid + t * 256;
        int r = v >> 5;
        int c4 = (v & 31) * 4;
        int gr = i0 + r; if (gr > N - 1) gr = N - 1;
        *reinterpret_cast<float4*>(&Ys[r][c4]) =
            *reinterpret_cast<const float4*>(&Y[(size_t)gr * NHID + c4]);
    }
    __syncthreads();
    const int c = tid & 63;
    const int rg = tid >> 6;
    float acc[4] = {0.f, 0.f, 0.f, 0.f};
    #pragma unroll 8
    for (int k = 0; k < NHID; ++k) {
        float w = Ws[k][c];
        #pragma unroll
        for (int j = 0; j < 4; ++j)
            acc[j] = fmaf(Ys[rg * 4 + j][k], w, acc[j]);
    }
    #pragma unroll
    for (int j = 0; j < 4; ++j) {
        int gr = i0 + rg * 4 + j;
        if (gr < N) H2s16[(size_t)gr * NCLS + c] = __float2half(acc[j] * dinv[gr]);
    }
}

// ---------------- AGG2 + softmax: two nodes per wave ----------------

__global__ __launch_bounds__(64) void agg2_kernel(const __half2* __restrict__ H2,
        const int* __restrict__ row_ptr, const int* __restrict__ col,
        const float* __restrict__ dinv, const float* __restrict__ b2,
        float* __restrict__ out, int N) {
    const int lane = threadIdx.x;
    const int node = blockIdx.x * 2 + (lane >> 5);
    const int c = lane & 31;             // col-pair 0..31
    if (node >= N) return;
    const int beg = row_ptr[node], end = row_ptr[node + 1];
    float2 f = __half22float2(H2[(size_t)node * 32 + c]);
    float ax = f.x, ay = f.y;
    int e = beg;
    for (; e + 8 <= end; e += 8) {
        float2 v[8];
        #pragma unroll
        for (int j = 0; j < 8; ++j) {
            int s = col[e + j];
            v[j] = __half22float2(H2[(size_t)s * 32 + c]);
        }
        #pragma unroll
        for (int j = 0; j < 8; ++j) { ax += v[j].x; ay += v[j].y; }
    }
    for (; e < end; ++e) {
        float2 v = __half22float2(H2[(size_t)col[e] * 32 + c]);
        ax += v.x; ay += v.y;
    }
    const float di = dinv[node];
    const float2 bb = reinterpret_cast<const float2*>(b2)[c];
    float vx = fmaf(ax, di, bb.x);
    float vy = fmaf(ay, di, bb.y);
    float m = fmaxf(vx, vy);
    #pragma unroll
    for (int d = 16; d >= 1; d >>= 1) m = fmaxf(m, __shfl_xor(m, d));
    float ex = __expf(vx - m), ey = __expf(vy - m);
    float sum = ex + ey;
    #pragma unroll
    for (int d = 16; d >= 1; d >>= 1) sum += __shfl_xor(sum, d);
    float2 o = {ex / sum, ey / sum};
    reinterpret_cast<float2*>(out)[(size_t)node * 32 + c] = o;
}

// ---------------- launch ----------------

extern "C" void kernel_launch(void* const* d_in, const int* in_sizes, int n_in,
                              void* d_out, int out_size, void* d_ws, size_t ws_size,
                              hipStream_t stream) {
    const float* x  = (const float*)d_in[0];
    const int*   ei = (const int*)d_in[1];
    const float* W1 = (const float*)d_in[2];
    const float* b1 = (const float*)d_in[3];
    const float* W2 = (const float*)d_in[4];
    const float* b2 = (const float*)d_in[5];
    const int N = in_sizes[0] / F_IN;
    const int E = in_sizes[1] / 2;
    const int* src = ei;
    const int* dst = ei + E;
    float* out = (float*)d_out;

    const int Npad = (N + 63) & ~63;
    const int Epad = (E + 63) & ~63;
    int*    cnt     = (int*)d_ws;                 // Npad
    int*    cursor  = cnt + Npad;                 // Npad
    int*    bcur    = cursor + Npad;              // 256
    int*    row_ptr = bcur + 256;                 // Npad (>= N+1)
    float*  dinv    = (float*)(row_ptr + Npad);   // Npad
    int*    col     = (int*)(dinv + Npad);        // Epad
    int*    bsum    = col + Epad;                 // 64
    int*    boff    = bsum + 64;                  // 64
    __half* Hs16    = (__half*)(boff + 64);       // Npad*128 halfs (12.8MB)
    float*  Y       = (float*)(Hs16 + (size_t)Npad * NHID);  // Npad*128 f32 (25.6MB)
    __half* H2s16   = Hs16;                       // reuse (Hs dead after agg1)
    short*  WhiT    = (short*)Y;                  // overlay Y start (256KB)
    short*  WloT    = WhiT + (size_t)F_IN * NHID;
    // bucket pair storage overlays Y at +512KB; dead before prepW/agg1 run
    int2*   pairs   = (int2*)((char*)Y + 512 * 1024);

    const int nb = (N + 1023) / 1024;
    const int nbuck = (N + 255) >> BSHIFT;                  // 196
    const int cap = (((E / nbuck) * 3 / 2) + 63) & ~63;     // ~12288

    hipMemsetAsync(cnt, 0, (size_t)(2 * Npad + 256) * sizeof(int), stream);
    count_kernel<<<(E + 255) / 256, 256, 0, stream>>>(dst, cnt, E);
    scan1_kernel<<<nb, 256, 0, stream>>>(cnt, row_ptr, dinv, bsum, N);
    scan2_kernel<<<1, 64, 0, stream>>>(bsum, boff, row_ptr, nb, N);
    scan3_kernel<<<(N + 255) / 256, 256, 0, stream>>>(row_ptr, boff, N);
    bin_kernel<<<(E + CHUNK - 1) / CHUNK, 256, 0, stream>>>(src, dst, pairs, bcur, E, cap);
    fill_b_kernel<<<nbuck * 4, 256, 0, stream>>>(pairs, bcur, row_ptr, cursor, col, cap);
    prepW_kernel<<<(F_IN * NHID) / 256, 256, 0, stream>>>(W1, WhiT, WloT);
    gemm1_mfma<<<(N + 63) / 64, 256, 0, stream>>>(x, WhiT, WloT, dinv, Hs16, N);
    agg1_kernel<<<N, 64, 0, stream>>>((const __half2*)Hs16, row_ptr, col, dinv, b1, Y);
    gemm2_kernel<<<(N + 15) / 16, 256, 0, stream>>>(Y, W2, dinv, H2s16, N);
    agg2_kernel<<<(N + 1) / 2, 64, 0, stream>>>((const __half2*)H2s16, row_ptr, col, dinv, b2, out, N);
}

// Round 5
// 209.093 us; speedup vs baseline: 2.4398x; 1.4259x over previous
//
#include <hip/hip_runtime.h>
#include <hip/hip_bf16.h>
#include <hip/hip_fp16.h>

// ---------------------------------------------------------------------------
// GCN 2-layer inference:
//   h1 = relu( D^-1/2 (A+I) D^-1/2 (x @ W1) + b1 )
//   out = softmax( D^-1/2 (A+I) D^-1/2 (h1 @ W2) + b2 )
//
// memset(bcur) -> bin (LDS counting-sort of edges by dst-bucket, dense run
// writes; ~77K device atomics total) -> count_b (per-bucket LDS histogram ->
// cnt, no device atomics) -> scan1/2/3 (row_ptr + dinv) -> fill_b (LDS
// cursor, bucket-local col writes) -> prepW -> gemm1_mfma (split-bf16 MFMA,
// *dinv -> fp16) -> agg1 (fp16 gather) -> gemm2 -> agg2 (+softmax).
//
// Round-4 lesson: per-edge global atomicAdd = far-atomic RMW (~32B HBM
// transaction each; 1.6M edges -> 50MB WRITE_SIZE, 70us). All per-edge
// atomics are now LDS-local within a 256-node bucket window.
// ---------------------------------------------------------------------------

#define F_IN 512
#define NHID 128
#define NCLS 64
#define BSHIFT 8           // 256 nodes per bucket
#define CHUNK 4096         // edges per bin block

typedef __attribute__((ext_vector_type(8))) short short8;
typedef __attribute__((ext_vector_type(4))) float f32x4;

__device__ __forceinline__ unsigned f2u(float f) { union { float f; unsigned u; } v; v.f = f; return v.u; }
__device__ __forceinline__ float u2f(unsigned u) { union { unsigned u; float f; } v; v.u = u; return v.f; }

// ---------------- binning: LDS counting-sort of 4096-edge chunks by bucket ----------------

__global__ __launch_bounds__(256) void bin_kernel(const int* __restrict__ src,
        const int* __restrict__ dst, int2* __restrict__ pairs,
        int* __restrict__ bcur, int E, int cap) {
    __shared__ int lcnt[256];
    __shared__ int lscan[256];
    __shared__ int gbase[256];
    __shared__ int wsum[4];
    __shared__ int2 stage[CHUNK];
    const int t = threadIdx.x;
    const int lane = t & 63, wid = t >> 6;
    const int e0 = blockIdx.x * CHUNK;
    const int n = min(CHUNK, E - e0);

    lcnt[t] = 0;
    __syncthreads();
    for (int i = t; i < n; i += 256)
        atomicAdd(&lcnt[dst[e0 + i] >> BSHIFT], 1);
    __syncthreads();
    const int v = lcnt[t];
    int s = v;
    #pragma unroll
    for (int d = 1; d < 64; d <<= 1) {
        int tt = __shfl_up(s, d);
        if (lane >= d) s += tt;
    }
    if (lane == 63) wsum[wid] = s;
    __syncthreads();
    int woff = 0;
    for (int w = 0; w < wid; ++w) woff += wsum[w];
    lscan[t] = woff + s - v;
    gbase[t] = v ? atomicAdd(&bcur[t], v) : 0;
    lcnt[t] = 0;
    __syncthreads();
    for (int i = t; i < n; i += 256) {
        int d = dst[e0 + i], sc = src[e0 + i];
        int b = d >> BSHIFT;
        int p = atomicAdd(&lcnt[b], 1);
        stage[lscan[b] + p] = make_int2(d, sc);
    }
    __syncthreads();
    // dense run writes: consecutive i within a run -> consecutive addresses
    for (int i = t; i < n; i += 256) {
        int2 pr = stage[i];
        int b = pr.x >> BSHIFT;
        int off = gbase[b] + (i - lscan[b]);
        if (off < cap) pairs[(size_t)b * cap + off] = pr;
    }
}

// ---------------- per-bucket degree count (LDS histogram, dense cnt write) ----------------

__global__ __launch_bounds__(256) void count_b_kernel(const int2* __restrict__ pairs,
        const int* __restrict__ bcur, int* __restrict__ cnt, int cap) {
    __shared__ int hist[256];
    const int b = blockIdx.x;
    const int t = threadIdx.x;
    hist[t] = 0;
    __syncthreads();
    const int n = min(bcur[b], cap);
    const int2* p = pairs + (size_t)b * cap;
    for (int i = t; i < n; i += 256)
        atomicAdd(&hist[p[i].x & 255], 1);
    __syncthreads();
    cnt[(b << BSHIFT) + t] = hist[t];
}

// ---------------- row_ptr scan ----------------

__global__ __launch_bounds__(256) void scan1_kernel(const int* __restrict__ cnt,
        int* __restrict__ row_ptr, float* __restrict__ dinv,
        int* __restrict__ bsum, int N) {
    __shared__ int wsum[4];
    const int tid = threadIdx.x;
    const int lane = tid & 63, wid = tid >> 6;
    const int base = blockIdx.x * 1024 + tid * 4;
    int4 v = {0, 0, 0, 0};
    if (base + 3 < N) {
        v = *reinterpret_cast<const int4*>(&cnt[base]);
    } else {
        if (base + 0 < N) v.x = cnt[base + 0];
        if (base + 1 < N) v.y = cnt[base + 1];
        if (base + 2 < N) v.z = cnt[base + 2];
        if (base + 3 < N) v.w = cnt[base + 3];
    }
    if (base + 0 < N) dinv[base + 0] = rsqrtf((float)v.x + 1.0f);
    if (base + 1 < N) dinv[base + 1] = rsqrtf((float)v.y + 1.0f);
    if (base + 2 < N) dinv[base + 2] = rsqrtf((float)v.z + 1.0f);
    if (base + 3 < N) dinv[base + 3] = rsqrtf((float)v.w + 1.0f);
    const int tsum = v.x + v.y + v.z + v.w;
    int s = tsum;
    #pragma unroll
    for (int d = 1; d < 64; d <<= 1) {
        int t = __shfl_up(s, d);
        if (lane >= d) s += t;
    }
    if (lane == 63) wsum[wid] = s;
    __syncthreads();
    int woff = 0;
    for (int w = 0; w < wid; ++w) woff += wsum[w];
    const int excl = woff + s - tsum;
    if (base + 0 < N) row_ptr[base + 0] = excl;
    if (base + 1 < N) row_ptr[base + 1] = excl + v.x;
    if (base + 2 < N) row_ptr[base + 2] = excl + v.x + v.y;
    if (base + 3 < N) row_ptr[base + 3] = excl + v.x + v.y + v.z;
    if (tid == 255) bsum[blockIdx.x] = excl + tsum;
}

__global__ __launch_bounds__(64) void scan2_kernel(const int* __restrict__ bsum,
        int* __restrict__ boff, int* __restrict__ row_ptr, int nb, int N) {
    const int lane = threadIdx.x;
    int v = (lane < nb) ? bsum[lane] : 0;
    int s = v;
    #pragma unroll
    for (int d = 1; d < 64; d <<= 1) {
        int t = __shfl_up(s, d);
        if (lane >= d) s += t;
    }
    if (lane < nb) boff[lane] = s - v;
    if (lane == 63) row_ptr[N] = s;
}

__global__ void scan3_kernel(int* __restrict__ row_ptr, const int* __restrict__ boff, int N) {
    int i = blockIdx.x * blockDim.x + threadIdx.x;
    if (i < N) row_ptr[i] += boff[i >> 10];
}

// ---------------- CSR placement: LDS cursor, bucket-local col writes ----------------

__global__ __launch_bounds__(512) void fill_b_kernel(const int2* __restrict__ pairs,
        const int* __restrict__ bcur, const int* __restrict__ row_ptr,
        int* __restrict__ col, int cap) {
    __shared__ int lcur[256];
    const int b = blockIdx.x;
    const int t = threadIdx.x;
    if (t < 256) lcur[t] = 0;
    __syncthreads();
    const int n = min(bcur[b], cap);
    const int2* p = pairs + (size_t)b * cap;
    for (int i = t; i < n; i += 512) {
        int2 pr = p[i];
        int pos = row_ptr[pr.x] + atomicAdd(&lcur[pr.x & 255], 1);
        col[pos] = pr.y;
    }
}

// ---------------- prepW: W1 [512][128] f32 -> WhiT/WloT [128][512] bf16 ----------------

__global__ __launch_bounds__(256) void prepW_kernel(const float* __restrict__ W1,
        short* __restrict__ WhiT, short* __restrict__ WloT) {
    int idx = blockIdx.x * 256 + threadIdx.x;
    int k = idx >> 7;
    int n = idx & 127;
    float w = W1[idx];
    unsigned u = f2u(w);
    short h = (short)(u >> 16);
    float hif = u2f(u & 0xffff0000u);
    short l = (short)(f2u(w - hif) >> 16);
    WhiT[(size_t)n * F_IN + k] = h;
    WloT[(size_t)n * F_IN + k] = l;
}

// ---------------- GEMM1: Hs16 = fp16((x @ W1) * dinv[row]) via split-bf16 MFMA ----------------

#define LDA 40

__global__ __launch_bounds__(256) void gemm1_mfma(
        const float* __restrict__ X, const short* __restrict__ WhiT,
        const short* __restrict__ WloT, const float* __restrict__ dinv,
        __half* __restrict__ Hs16, int M) {
    __shared__ short Ahi[64 * LDA];
    __shared__ short Alo[64 * LDA];
    const int tid = threadIdx.x;
    const int lane = tid & 63;
    const int wid = tid >> 6;
    const int m0 = blockIdx.x * 64;
    const int n0 = wid * 32;
    const int l15 = lane & 15;
    const int kc = lane >> 4;

    const int sr = tid >> 2;
    const int sc = tid & 3;
    int grow = m0 + sr; if (grow > M - 1) grow = M - 1;
    const float* xp = X + (size_t)grow * F_IN + sc * 8;
    short* ahw = &Ahi[sr * LDA + sc * 8];
    short* alw = &Alo[sr * LDA + sc * 8];

    const short* bhp = WhiT + (size_t)(n0 + l15) * F_IN + kc * 8;
    const short* blp = WloT + (size_t)(n0 + l15) * F_IN + kc * 8;

    f32x4 acc[4][2];
    #pragma unroll
    for (int i = 0; i < 4; ++i)
        #pragma unroll
        for (int j = 0; j < 2; ++j)
            acc[i][j] = (f32x4){0.f, 0.f, 0.f, 0.f};

    for (int k0 = 0; k0 < F_IN; k0 += 32) {
        float4 a0 = *reinterpret_cast<const float4*>(xp + k0);
        float4 a1 = *reinterpret_cast<const float4*>(xp + k0 + 4);
        float av[8] = {a0.x, a0.y, a0.z, a0.w, a1.x, a1.y, a1.z, a1.w};
        short8 vh, vl;
        #pragma unroll
        for (int j = 0; j < 8; ++j) {
            unsigned u = f2u(av[j]);
            vh[j] = (short)(u >> 16);
            float hif = u2f(u & 0xffff0000u);
            vl[j] = (short)(f2u(av[j] - hif) >> 16);
        }
        __syncthreads();
        *reinterpret_cast<short8*>(ahw) = vh;
        *reinterpret_cast<short8*>(alw) = vl;
        short8 bh0 = *reinterpret_cast<const short8*>(bhp + k0);
        short8 bl0 = *reinterpret_cast<const short8*>(blp + k0);
        short8 bh1 = *reinterpret_cast<const short8*>(bhp + 16 * F_IN + k0);
        short8 bl1 = *reinterpret_cast<const short8*>(blp + 16 * F_IN + k0);
        __syncthreads();
        #pragma unroll
        for (int mt = 0; mt < 4; ++mt) {
            const short8 ah = *reinterpret_cast<const short8*>(&Ahi[(mt * 16 + l15) * LDA + kc * 8]);
            const short8 al = *reinterpret_cast<const short8*>(&Alo[(mt * 16 + l15) * LDA + kc * 8]);
            acc[mt][0] = __builtin_amdgcn_mfma_f32_16x16x32_bf16(ah, bh0, acc[mt][0], 0, 0, 0);
            acc[mt][0] = __builtin_amdgcn_mfma_f32_16x16x32_bf16(ah, bl0, acc[mt][0], 0, 0, 0);
            acc[mt][0] = __builtin_amdgcn_mfma_f32_16x16x32_bf16(al, bh0, acc[mt][0], 0, 0, 0);
            acc[mt][1] = __builtin_amdgcn_mfma_f32_16x16x32_bf16(ah, bh1, acc[mt][1], 0, 0, 0);
            acc[mt][1] = __builtin_amdgcn_mfma_f32_16x16x32_bf16(ah, bl1, acc[mt][1], 0, 0, 0);
            acc[mt][1] = __builtin_amdgcn_mfma_f32_16x16x32_bf16(al, bh1, acc[mt][1], 0, 0, 0);
        }
    }
    #pragma unroll
    for (int mt = 0; mt < 4; ++mt) {
        #pragma unroll
        for (int r = 0; r < 4; ++r) {
            int row = m0 + mt * 16 + kc * 4 + r;
            if (row < M) {
                float di = dinv[row];
                #pragma unroll
                for (int nt = 0; nt < 2; ++nt) {
                    Hs16[(size_t)row * NHID + n0 + nt * 16 + l15] =
                        __float2half(acc[mt][nt][r] * di);
                }
            }
        }
    }
}

// ---------------- AGG1: Y = relu(dinv[i]*(Hs[i] + sum Hs[src]) + b1) ----------------

__global__ __launch_bounds__(64) void agg1_kernel(const __half2* __restrict__ Hs,
        const int* __restrict__ row_ptr, const int* __restrict__ col,
        const float* __restrict__ dinv, const float* __restrict__ b1,
        float* __restrict__ Y) {
    const int i = blockIdx.x;
    const int c = threadIdx.x;           // col-pair 0..63
    const int beg = row_ptr[i], end = row_ptr[i + 1];
    float2 f = __half22float2(Hs[(size_t)i * 64 + c]);
    float ax = f.x, ay = f.y;
    int e = beg;
    for (; e + 8 <= end; e += 8) {
        float2 v[8];
        #pragma unroll
        for (int j = 0; j < 8; ++j) {
            int s = col[e + j];
            v[j] = __half22float2(Hs[(size_t)s * 64 + c]);
        }
        #pragma unroll
        for (int j = 0; j < 8; ++j) { ax += v[j].x; ay += v[j].y; }
    }
    for (; e < end; ++e) {
        float2 v = __half22float2(Hs[(size_t)col[e] * 64 + c]);
        ax += v.x; ay += v.y;
    }
    const float di = dinv[i];
    const float2 bb = reinterpret_cast<const float2*>(b1)[c];
    float2 o;
    o.x = fmaxf(fmaf(ax, di, bb.x), 0.0f);
    o.y = fmaxf(fmaf(ay, di, bb.y), 0.0f);
    *reinterpret_cast<float2*>(&Y[(size_t)i * NHID + 2 * c]) = o;
}

// ---------------- GEMM2: H2s16 = fp16((Y @ W2) * dinv[row])  [N,64] ----------------

__global__ __launch_bounds__(256) void gemm2_kernel(const float* __restrict__ Y,
        const float* __restrict__ W2, const float* __restrict__ dinv,
        __half* __restrict__ H2s16, int N) {
    __shared__ float Ws[NHID][NCLS];
    __shared__ float Ys[16][NHID];
    const int tid = threadIdx.x;
    const int i0 = blockIdx.x * 16;
    #pragma unroll
    for (int t = 0; t < 8; ++t) {
        int v = tid + t * 256;
        int k = v >> 4;
        int c4 = (v & 15) * 4;
        *reinterpret_cast<float4*>(&Ws[k][c4]) =
            *reinterpret_cast<const float4*>(&W2[(size_t)k * NCLS + c4]);
    }
    #pragma unroll
    for (int t = 0; t < 2; ++t) {
        int v = tid + t * 256;
        int r = v >> 5;
        int c4 = (v & 31) * 4;
        int gr = i0 + r; if (gr > N - 1) gr = N - 1;
        *reinterpret_cast<float4*>(&Ys[r][c4]) =
            *reinterpret_cast<const float4*>(&Y[(size_t)gr * NHID + c4]);
    }
    __syncthreads();
    const int c = tid & 63;
    const int rg = tid >> 6;
    float acc[4] = {0.f, 0.f, 0.f, 0.f};
    #pragma unroll 8
    for (int k = 0; k < NHID; ++k) {
        float w = Ws[k][c];
        #pragma unroll
        for (int j = 0; j < 4; ++j)
            acc[j] = fmaf(Ys[rg * 4 + j][k], w, acc[j]);
    }
    #pragma unroll
    for (int j = 0; j < 4; ++j) {
        int gr = i0 + rg * 4 + j;
        if (gr < N) H2s16[(size_t)gr * NCLS + c] = __float2half(acc[j] * dinv[gr]);
    }
}

// ---------------- AGG2 + softmax: two nodes per wave ----------------

__global__ __launch_bounds__(64) void agg2_kernel(const __half2* __restrict__ H2,
        const int* __restrict__ row_ptr, const int* __restrict__ col,
        const float* __restrict__ dinv, const float* __restrict__ b2,
        float* __restrict__ out, int N) {
    const int lane = threadIdx.x;
    const int node = blockIdx.x * 2 + (lane >> 5);
    const int c = lane & 31;             // col-pair 0..31
    if (node >= N) return;
    const int beg = row_ptr[node], end = row_ptr[node + 1];
    float2 f = __half22float2(H2[(size_t)node * 32 + c]);
    float ax = f.x, ay = f.y;
    int e = beg;
    for (; e + 8 <= end; e += 8) {
        float2 v[8];
        #pragma unroll
        for (int j = 0; j < 8; ++j) {
            int s = col[e + j];
            v[j] = __half22float2(H2[(size_t)s * 32 + c]);
        }
        #pragma unroll
        for (int j = 0; j < 8; ++j) { ax += v[j].x; ay += v[j].y; }
    }
    for (; e < end; ++e) {
        float2 v = __half22float2(H2[(size_t)col[e] * 32 + c]);
        ax += v.x; ay += v.y;
    }
    const float di = dinv[node];
    const float2 bb = reinterpret_cast<const float2*>(b2)[c];
    float vx = fmaf(ax, di, bb.x);
    float vy = fmaf(ay, di, bb.y);
    float m = fmaxf(vx, vy);
    #pragma unroll
    for (int d = 16; d >= 1; d >>= 1) m = fmaxf(m, __shfl_xor(m, d));
    float ex = __expf(vx - m), ey = __expf(vy - m);
    float sum = ex + ey;
    #pragma unroll
    for (int d = 16; d >= 1; d >>= 1) sum += __shfl_xor(sum, d);
    float2 o = {ex / sum, ey / sum};
    reinterpret_cast<float2*>(out)[(size_t)node * 32 + c] = o;
}

// ---------------- launch ----------------

extern "C" void kernel_launch(void* const* d_in, const int* in_sizes, int n_in,
                              void* d_out, int out_size, void* d_ws, size_t ws_size,
                              hipStream_t stream) {
    const float* x  = (const float*)d_in[0];
    const int*   ei = (const int*)d_in[1];
    const float* W1 = (const float*)d_in[2];
    const float* b1 = (const float*)d_in[3];
    const float* W2 = (const float*)d_in[4];
    const float* b2 = (const float*)d_in[5];
    const int N = in_sizes[0] / F_IN;
    const int E = in_sizes[1] / 2;
    const int* src = ei;
    const int* dst = ei + E;
    float* out = (float*)d_out;

    const int Npad  = (N + 63) & ~63;
    const int Nb256 = (N + 255) & ~255;           // cnt size (bucket-dense)
    const int Epad  = (E + 63) & ~63;
    int*    cnt     = (int*)d_ws;                 // Nb256
    int*    bcur    = cnt + Nb256;                // 256
    int*    row_ptr = bcur + 256;                 // Npad (>= N+1)
    float*  dinv    = (float*)(row_ptr + Npad);   // Npad
    int*    col     = (int*)(dinv + Npad);        // Epad
    int*    bsum    = col + Epad;                 // 64
    int*    boff    = bsum + 64;                  // 64
    __half* Hs16    = (__half*)(boff + 64);       // Npad*128 halfs (12.8MB)
    float*  Y       = (float*)(Hs16 + (size_t)Npad * NHID);  // Npad*128 f32 (25.6MB)
    __half* H2s16   = Hs16;                       // reuse (Hs dead after agg1)
    short*  WhiT    = (short*)Y;                  // overlay Y start (256KB)
    short*  WloT    = WhiT + (size_t)F_IN * NHID;
    // bucket pair storage overlays Y at +512KB; dead before agg1 writes Y
    int2*   pairs   = (int2*)((char*)Y + 512 * 1024);

    const int nb = (N + 1023) / 1024;
    const int nbuck = (N + 255) >> BSHIFT;                  // 196
    const int cap = (((E / nbuck) * 3 / 2) + 63) & ~63;     // ~12288

    hipMemsetAsync(bcur, 0, 256 * sizeof(int), stream);
    bin_kernel<<<(E + CHUNK - 1) / CHUNK, 256, 0, stream>>>(src, dst, pairs, bcur, E, cap);
    count_b_kernel<<<nbuck, 256, 0, stream>>>(pairs, bcur, cnt, cap);
    scan1_kernel<<<nb, 256, 0, stream>>>(cnt, row_ptr, dinv, bsum, N);
    scan2_kernel<<<1, 64, 0, stream>>>(bsum, boff, row_ptr, nb, N);
    scan3_kernel<<<(N + 255) / 256, 256, 0, stream>>>(row_ptr, boff, N);
    fill_b_kernel<<<nbuck, 512, 0, stream>>>(pairs, bcur, row_ptr, col, cap);
    prepW_kernel<<<(F_IN * NHID) / 256, 256, 0, stream>>>(W1, WhiT, WloT);
    gemm1_mfma<<<(N + 63) / 64, 256, 0, stream>>>(x, WhiT, WloT, dinv, Hs16, N);
    agg1_kernel<<<N, 64, 0, stream>>>((const __half2*)Hs16, row_ptr, col, dinv, b1, Y);
    gemm2_kernel<<<(N + 15) / 16, 256, 0, stream>>>(Y, W2, dinv, H2s16, N);
    agg2_kernel<<<(N + 1) / 2, 64, 0, stream>>>((const __half2*)H2s16, row_ptr, col, dinv, b2, out, N);
}